// Round 14
// baseline (268.477 us; speedup 1.0000x reference)
//
#include <hip/hip_runtime.h>
#include <stdint.h>

#define LDS_AS __attribute__((address_space(3)))
#define GLB_AS __attribute__((address_space(1)))

typedef unsigned short bfu;                                    // bf16 bit pattern
typedef __attribute__((ext_vector_type(8))) short short8;      // MFMA A/B frag (8 bf16)
typedef __attribute__((ext_vector_type(16))) float f32x16;     // 32x32 MFMA C/D frag

static constexpr int B_  = 8192;
static constexpr int D_  = 1024;
static constexpr int E_  = 16;
static constexpr int H_  = 256;
static constexpr int EH_ = E_ * H_;     // 4096

__device__ __forceinline__ bfu f2b(float f) {
  unsigned u = __float_as_uint(f);
  u = (u + 0x7FFFu + ((u >> 16) & 1u)) >> 16;   // RNE, finite data
  return (bfu)u;
}
__device__ __forceinline__ float b2f(bfu b) {
  return __uint_as_float(((unsigned)b) << 16);
}

__device__ __forceinline__ void gload_lds16(const bfu* g, bfu* l) {
  __builtin_amdgcn_global_load_lds((const GLB_AS void*)g, (LDS_AS void*)l, 16, 0, 0);
}

// ------ fused prep+router: blocks 0..2047 convert, 2048..2559 route ------
__global__ __launch_bounds__(256)
void k_prep(const float* __restrict__ x, bfu* __restrict__ xb,
            const float* __restrict__ W1, bfu* __restrict__ W1b,
            const float* __restrict__ W2, bfu* __restrict__ W2t,
            const float* __restrict__ cond, const float* __restrict__ Wr1,
            const float* __restrict__ br1, const float* __restrict__ Wr2,
            const float* __restrict__ br2, float* __restrict__ route) {
  __shared__ float sW1[128][65];
  __shared__ float sW2[16][129];
  __shared__ float sb1[128], sb2[16];
  __shared__ float sc[2][64];
  __shared__ float srh[2][128];
  const int t = threadIdx.x;
  const int bid = (int)blockIdx.x;
  if (bid < 2048) {
    const int total = 2048 * 256;
    const int gid = bid * 256 + t;
    const int n1 = B_ * D_ / 4;
    const int n2 = EH_ * D_ / 4;
    const int n3 = E_ * D_ * 64;
    for (int i = gid; i < n1; i += total) {
      float4 v = reinterpret_cast<const float4*>(x)[i];
      ushort4 o;
      o.x = f2b(v.x); o.y = f2b(v.y); o.z = f2b(v.z); o.w = f2b(v.w);
      reinterpret_cast<ushort4*>(xb)[i] = o;
    }
    for (int i = gid; i < n2; i += total) {
      float4 v = reinterpret_cast<const float4*>(W1)[i];
      ushort4 o;
      o.x = f2b(v.x); o.y = f2b(v.y); o.z = f2b(v.z); o.w = f2b(v.w);
      reinterpret_cast<ushort4*>(W1b)[i] = o;
    }
    for (int i = gid; i < n3; i += total) {
      const int h4 = i & 63;
      const int d  = (i >> 6) & (D_ - 1);
      const int e  = i >> 16;
      float4 v = reinterpret_cast<const float4*>(W2)[((e << 10) | d) * 64 + h4];
      ushort4 o;
      o.x = f2b(v.x); o.y = f2b(v.y); o.z = f2b(v.z); o.w = f2b(v.w);
      reinterpret_cast<ushort4*>(W2t + ((size_t)d << 12) + (e << 8))[h4] = o;
    }
    return;
  }
  // ---- router: 512 blocks x 16 rows ----
  for (int i = t; i < 128 * 64; i += 256) sW1[i >> 6][i & 63] = Wr1[i];
  for (int i = t; i < 16 * 128; i += 256) sW2[i >> 7][i & 127] = Wr2[i];
  if (t < 128) sb1[t] = br1[t];
  else if (t < 144) sb2[t - 128] = br2[t - 128];
  const int rowBase = (bid - 2048) * 16;
  for (int r0 = 0; r0 < 16; r0 += 2) {
    __syncthreads();
    if (t < 128) sc[t >> 6][t & 63] = cond[(size_t)(rowBase + r0 + (t >> 6)) * 64 + (t & 63)];
    __syncthreads();
    {
      const int half = t >> 7, j = t & 127;
      float a = sb1[j];
      #pragma unroll 16
      for (int c = 0; c < 64; ++c) a = fmaf(sc[half][c], sW1[j][c], a);
      srh[half][j] = fmaxf(a, 0.f);
    }
    __syncthreads();
    if (t < 32) {
      const int half = t >> 4, e = t & 15;
      float a = sb2[e];
      #pragma unroll 16
      for (int k = 0; k < 128; ++k) a = fmaf(srh[half][k], sW2[e][k], a);
      float mx = a;
      #pragma unroll
      for (int m = 8; m; m >>= 1) mx = fmaxf(mx, __shfl_xor(mx, m, 16));
      float p = __expf(a - mx);
      float s = p;
      #pragma unroll
      for (int m = 8; m; m >>= 1) s += __shfl_xor(s, m, 16);
      route[(size_t)(rowBase + r0 + half) * 16 + e] = p / s;
    }
  }
}

// ---- 256x256 GEMM-BT, 16 waves (4 wr x 4 wc), wave-out 64x64, BK=64, dbuf ----
// 4 waves/SIMD in ONE block -> intra-CU TLP. Per K64-tile per wave:
// 16 ds_read_b128 + 16 MFMA(32x32x16), one __syncthreads.
// LDS per buf 32KB: A 256x128B @0, B 256x128B @32KB(byte base 32768? see aKs/bKs).
// Swizzle: 128B rows, 8 slots; store slot=(tid&7)^(row&7); read kterm XOR (l&7)<<4.
// C/D: col=l&31, row=(r&3)+8*(r>>2)+4*(l>>5) [HW-verified m74/m101].
// EPI=1: PERSISTENT (grid 256): 2 tiles/block, same brow (A-panel L2 reuse);
//        bf16 relu(acc+b1)*route -> Hp.
// EPI=2: grid 256, split-K x2; chunk0 -> f32 out, chunk1 -> bf16 partial.

#define STAGE_TILE_P(buf_)                                                        \
  do {                                                                            \
    gload_lds16(pB0, lds + (buf_) * 32768 + 16384 + tid * 8);                     \
    gload_lds16(pB1, lds + (buf_) * 32768 + 24576 + tid * 8);                     \
    gload_lds16(pA0, lds + (buf_) * 32768 + tid * 8);                             \
    gload_lds16(pA1, lds + (buf_) * 32768 + 8192 + tid * 8);                      \
    pA0 += 64; pA1 += 64; pB0 += 64; pB1 += 64;                                   \
  } while (0)

// frag reads (BYTE units): runtime base (per ks) + compile-time imm (mt/nt)
#define LDA32(dst_, buf_, ksv_, mt_)                                              \
  dst_ = *reinterpret_cast<const short8*>(                                        \
      ldsC + ((buf_) << 16) + aKs[ksv_] + ((mt_) << 12))

#define LDB32(dst_, buf_, ksv_, nt_)                                              \
  dst_ = *reinterpret_cast<const short8*>(                                        \
      ldsC + ((buf_) << 16) + bKs[ksv_] + ((nt_) << 12))

#define LDAB2(dstA_, dstB_, buf_, ksv_)                                           \
  do {                                                                            \
    LDA32(dstA_[0], buf_, ksv_, 0); LDA32(dstA_[1], buf_, ksv_, 1);               \
    LDB32(dstB_[0], buf_, ksv_, 0); LDB32(dstB_[1], buf_, ksv_, 1);               \
  } while (0)

#define MFMA4(AF_, BF_)                                                           \
  _Pragma("unroll") for (int mt_ = 0; mt_ < 2; ++mt_)                             \
  _Pragma("unroll") for (int nt_ = 0; nt_ < 2; ++nt_)                             \
    acc[mt_][nt_] = __builtin_amdgcn_mfma_f32_32x32x16_bf16(                      \
        AF_[mt_], BF_[nt_], acc[mt_][nt_], 0, 0, 0);

#define TILE_COMPUTE(c_)                                                          \
  do {                                                                            \
    LDAB2(aP_, bP_, (c_), 0);                                                     \
    LDAB2(aN_, bN_, (c_), 1);                                                     \
    MFMA4(aP_, bP_);                                                              \
    LDAB2(aP_, bP_, (c_), 2);                                                     \
    MFMA4(aN_, bN_);                                                              \
    LDAB2(aN_, bN_, (c_), 3);                                                     \
    MFMA4(aP_, bP_);                                                              \
    MFMA4(aN_, bN_);                                                              \
  } while (0)

#define GEMM_KLOOP()                                                              \
  do {                                                                            \
    STAGE_TILE_P(0);                                                              \
    __syncthreads();                                                              \
    for (int it = 0; it < (nkt >> 1); ++it) {                                     \
      const int T = it << 1;                                                      \
      STAGE_TILE_P(1);                                                            \
      TILE_COMPUTE(0);                                                            \
      __syncthreads();                                                            \
      if (T + 2 < nkt) STAGE_TILE_P(0);                                           \
      TILE_COMPUTE(1);                                                            \
      __syncthreads();                                                            \
    }                                                                             \
  } while (0)

template <int EPI>
__global__ __launch_bounds__(1024, 4)
void k_gemm16(const bfu* __restrict__ A, int lda,
              const bfu* __restrict__ Bm, int ldb,
              int nkt,                      // K64-tiles (per chunk), even, >= 2
              float* __restrict__ outF, bfu* __restrict__ outB, int ldc,
              const float* __restrict__ route, const float* __restrict__ bias1) {
  __shared__ __align__(16) bfu lds[65536];  // 128 KiB: 2 bufs x (A 32KB | B 32KB)
  const char* ldsC = reinterpret_cast<const char*>(lds);
  const int tid = (int)threadIdx.x;
  const int w = tid >> 6, l = tid & 63;
  const int wr = w >> 2, wc = w & 3;                 // 4 x 4 waves
  const int l31 = l & 31, lhi = l >> 5;
  const unsigned axor = (unsigned)((l & 7) << 4);

  unsigned aKs[4], bKs[4];
  #pragma unroll
  for (int ks = 0; ks < 4; ++ks) {
    const unsigned kterm = ((unsigned)((ks << 5) | (lhi << 4))) ^ axor;
    aKs[ks] = (unsigned)((wr * 64 + l31) * 128) + kterm;
    bKs[ks] = (unsigned)(32768 + (wc * 64 + l31) * 128) + kterm;
  }

  const int bid = (int)blockIdx.x;
  const int xcd = bid & 7;
  const int srow = tid >> 3;                                     // 0..127
  const int sswz = ((tid & 7) ^ (srow & 7)) << 3;                // element offset

  int brow, bcolBase, nTiles, chunk = 0, kOff = 0;
  if (EPI == 1) {
    // PERSISTENT grid 256: xcd owns an 8x8 tile square; block does 2 tiles,
    // same row-panel, cols (i&3) and (i&3)+4 within the square.
    const int i = bid >> 3;                       // 0..31
    brow = (((xcd >> 1) << 3) + (i >> 2)) << 8;
    bcolBase = (((xcd & 1) << 3) + (i & 3)) << 8;
    nTiles = 2;
  } else {
    const int i = bid >> 3;                       // grid 256: 4-row slab per chunk
    chunk = i >> 4;
    const int ii = i & 15;
    brow = ((xcd << 2) + (ii >> 2)) << 8;
    bcolBase = (ii & 3) << 8;
    kOff = chunk * (nkt << 6);
    nTiles = 1;
  }

  for (int t2 = 0; t2 < nTiles; ++t2) {
    const int bcol = bcolBase + t2 * 1024;        // +4 coltiles for tile 2

    // hoisted per-lane staging addresses (tile 0 of this output tile)
    const bfu* pA0 = A + (size_t)(brow + srow) * lda + kOff + sswz;
    const bfu* pA1 = pA0 + (size_t)128 * lda;
    const bfu* pB0 = Bm + (size_t)(bcol + srow) * ldb + kOff + sswz;
    const bfu* pB1 = pB0 + (size_t)128 * ldb;

    f32x16 acc[2][2] = {};
    short8 aP_[2], aN_[2], bP_[2], bN_[2];

    GEMM_KLOOP();

    // ---------- coalesced epilogue via padded LDS bounce ----------
    if (EPI == 1 || chunk == 1) {
      // bf16: 2 slices of 128 rows; stride 264 bfu (67.6 KB)
      const int STR = 264;
      #pragma unroll
      for (int s = 0; s < 2; ++s) {
        if ((wr >> 1) == s) {
          #pragma unroll
          for (int mt = 0; mt < 2; ++mt) {
            #pragma unroll
            for (int nt = 0; nt < 2; ++nt) {
              const int col = wc * 64 + nt * 32 + l31;
              float bz = 0.f;
              if (EPI == 1) bz = bias1[bcol + col];
              #pragma unroll
              for (int r = 0; r < 16; ++r) {
                const int rloc = (r & 3) + 8 * (r >> 2) + 4 * lhi;     // 0..31
                const int lrow = (wr & 1) * 64 + mt * 32 + rloc;       // 0..127
                float v = acc[mt][nt][r];
                if (EPI == 1) {
                  const int rowg = brow + s * 128 + lrow;
                  v = fmaxf(v + bz, 0.f) * route[(size_t)rowg * E_ + (bcol >> 8)];
                }
                lds[lrow * STR + col] = f2b(v);
              }
            }
          }
        }
        __syncthreads();
        #pragma unroll
        for (int i = 0; i < 4; ++i) {
          const int id = i * 1024 + tid;            // 4096 x 16B chunks
          const int row = id >> 5, c16 = id & 31;   // row 0..127
          *reinterpret_cast<short8*>(outB + (size_t)(brow + s * 128 + row) * ldc +
                                     bcol + c16 * 8) =
              *reinterpret_cast<const short8*>(lds + row * STR + c16 * 8);
        }
        __syncthreads();
      }
    } else {
      // f32: 4 slices of 64 rows keyed by wr; stride 260 f32 (66.5 KB)
      const int STRF = 260;
      float* sF = reinterpret_cast<float*>(lds);
      #pragma unroll
      for (int s = 0; s < 4; ++s) {
        if (wr == s) {
          #pragma unroll
          for (int mt = 0; mt < 2; ++mt) {
            #pragma unroll
            for (int nt = 0; nt < 2; ++nt) {
              const int col = wc * 64 + nt * 32 + l31;
              #pragma unroll
              for (int r = 0; r < 16; ++r) {
                const int rloc = (r & 3) + 8 * (r >> 2) + 4 * lhi;     // 0..31
                sF[(mt * 32 + rloc) * STRF + col] = acc[mt][nt][r];
              }
            }
          }
        }
        __syncthreads();
        #pragma unroll
        for (int i = 0; i < 4; ++i) {
          const int id = i * 1024 + tid;            // 4096 x 16B chunks
          const int row = id >> 6, c4 = id & 63;    // row 0..63
          *reinterpret_cast<float4*>(outF + (size_t)(brow + s * 64 + row) * ldc +
                                     bcol + c4 * 4) =
              *reinterpret_cast<const float4*>(sF + row * STRF + c4 * 4);
        }
        __syncthreads();
      }
    }
  }
}

// ---------------- reduce: out += P1 + route @ b2 ----------------
__global__ __launch_bounds__(256)
void k_reduce(float* __restrict__ out, const bfu* __restrict__ P1,
              const float* __restrict__ route, const float* __restrict__ b2) {
  __shared__ float sb2[E_ * D_];   // 64 KiB
  for (int i = threadIdx.x; i < E_ * D_; i += 256) sb2[i] = b2[i];
  __syncthreads();
  const int total = (B_ * D_) / 4;
  for (int idx = blockIdx.x * 256 + threadIdx.x; idx < total; idx += gridDim.x * 256) {
    const int b = idx >> 8;
    const int d4 = (idx & 255) * 4;
    float4 o = reinterpret_cast<float4*>(out)[idx];
    ushort4 p = reinterpret_cast<const ushort4*>(P1)[idx];
    o.x += b2f(p.x); o.y += b2f(p.y); o.z += b2f(p.z); o.w += b2f(p.w);
    const float* rr = route + (size_t)b * E_;
    #pragma unroll
    for (int e = 0; e < E_; ++e) {
      const float r = rr[e];
      const float* bb = sb2 + e * D_ + d4;
      o.x = fmaf(r, bb[0], o.x);
      o.y = fmaf(r, bb[1], o.y);
      o.z = fmaf(r, bb[2], o.z);
      o.w = fmaf(r, bb[3], o.w);
    }
    reinterpret_cast<float4*>(out)[idx] = o;
  }
}

// ---------------- launch ----------------
extern "C" void kernel_launch(void* const* d_in, const int* in_sizes, int n_in,
                              void* d_out, int out_size, void* d_ws, size_t ws_size,
                              hipStream_t stream) {
  const float* x    = (const float*)d_in[0];
  const float* cond = (const float*)d_in[1];
  const float* W1   = (const float*)d_in[2];
  const float* b1   = (const float*)d_in[3];
  const float* W2   = (const float*)d_in[4];
  const float* b2   = (const float*)d_in[5];
  const float* Wr1  = (const float*)d_in[6];
  const float* br1  = (const float*)d_in[7];
  const float* Wr2  = (const float*)d_in[8];
  const float* br2  = (const float*)d_in[9];
  float* out = (float*)d_out;

  // ws layout (96.5 MB):
  // [Hp 64MB][W2t 8MB][route 0.5MB][W1b 8MB][xb 16MB (= P1 after GEMM1)]
  char* p = (char*)d_ws;
  bfu*   Hp    = (bfu*)p;                 p += (size_t)B_ * EH_ * 2;
  bfu*   W2t   = (bfu*)p;                 p += (size_t)D_ * EH_ * 2;
  float* route = (float*)p;               p += (size_t)B_ * E_ * 4;
  bfu*   W1b   = (bfu*)p;                 p += (size_t)EH_ * D_ * 2;
  bfu*   xb    = (bfu*)p;                 /* B_*D_*2 = 16MB */
  bfu*   P1b   = xb;                      // alias: xb dead after GEMM1

  // prep (blocks 0..2047) + router (blocks 2048..2559)
  k_prep<<<2560, 256, 0, stream>>>(x, xb, W1, W1b, W2, W2t,
                                   cond, Wr1, br1, Wr2, br2, route);

  // GEMM1: Hp[8192,4096] = relu(xb @ W1b^T + b1) * route
  // persistent grid 256, 2 tiles/block (same row-panel)
  k_gemm16<1><<<dim3(256), 1024, 0, stream>>>(
      xb, D_, W1b, D_, D_ / 64, nullptr, Hp, EH_, route, b1);

  // GEMM2: out/P1 = Hp @ W2t^T, split-K x2  (256 blocks)
  k_gemm16<2><<<dim3((B_ / 256) * (D_ / 256) * 2), 1024, 0, stream>>>(
      Hp, EH_, W2t, EH_, (EH_ / 64) / 2, out, P1b, D_, nullptr, nullptr);

  // out += P1 + route @ b2
  k_reduce<<<1024, 256, 0, stream>>>(out, P1b, route, b2);
}

// Round 15
// 199.324 us; speedup vs baseline: 1.3469x; 1.3469x over previous
//
#include <hip/hip_runtime.h>
#include <stdint.h>

#define LDS_AS __attribute__((address_space(3)))
#define GLB_AS __attribute__((address_space(1)))

typedef unsigned short bfu;                                    // bf16 bit pattern
typedef __attribute__((ext_vector_type(8))) short short8;      // MFMA A/B frag (8 bf16)
typedef __attribute__((ext_vector_type(16))) float f32x16;     // 32x32 MFMA C/D frag

static constexpr int B_  = 8192;
static constexpr int D_  = 1024;
static constexpr int E_  = 16;
static constexpr int H_  = 256;
static constexpr int EH_ = E_ * H_;     // 4096

__device__ __forceinline__ bfu f2b(float f) {
  unsigned u = __float_as_uint(f);
  u = (u + 0x7FFFu + ((u >> 16) & 1u)) >> 16;   // RNE, finite data
  return (bfu)u;
}
__device__ __forceinline__ float b2f(bfu b) {
  return __uint_as_float(((unsigned)b) << 16);
}

__device__ __forceinline__ void gload_lds16(const bfu* g, bfu* l) {
  __builtin_amdgcn_global_load_lds((const GLB_AS void*)g, (LDS_AS void*)l, 16, 0, 0);
}

// ---------------- converts (no LDS -> full occupancy) ----------------
__global__ __launch_bounds__(256)
void k_prep(const float* __restrict__ x, bfu* __restrict__ xb,
            const float* __restrict__ W1, bfu* __restrict__ W1b,
            const float* __restrict__ W2, bfu* __restrict__ W2t) {
  const int total = (int)gridDim.x * 256;
  const int gid = (int)blockIdx.x * 256 + (int)threadIdx.x;
  const int n1 = B_ * D_ / 4;
  const int n2 = EH_ * D_ / 4;
  const int n3 = E_ * D_ * 64;
  for (int i = gid; i < n1; i += total) {
    float4 v = reinterpret_cast<const float4*>(x)[i];
    ushort4 o;
    o.x = f2b(v.x); o.y = f2b(v.y); o.z = f2b(v.z); o.w = f2b(v.w);
    reinterpret_cast<ushort4*>(xb)[i] = o;
  }
  for (int i = gid; i < n2; i += total) {
    float4 v = reinterpret_cast<const float4*>(W1)[i];
    ushort4 o;
    o.x = f2b(v.x); o.y = f2b(v.y); o.z = f2b(v.z); o.w = f2b(v.w);
    reinterpret_cast<ushort4*>(W1b)[i] = o;
  }
  for (int i = gid; i < n3; i += total) {
    const int h4 = i & 63;
    const int d  = (i >> 6) & (D_ - 1);
    const int e  = i >> 16;
    float4 v = reinterpret_cast<const float4*>(W2)[((e << 10) | d) * 64 + h4];
    ushort4 o;
    o.x = f2b(v.x); o.y = f2b(v.y); o.z = f2b(v.z); o.w = f2b(v.w);
    reinterpret_cast<ushort4*>(W2t + ((size_t)d << 12) + (e << 8))[h4] = o;
  }
}

// ---------------- router (fp32, exact) ----------------
__global__ __launch_bounds__(256)
void k_router(const float* __restrict__ cond, const float* __restrict__ Wr1,
              const float* __restrict__ br1, const float* __restrict__ Wr2,
              const float* __restrict__ br2, float* __restrict__ route) {
  __shared__ float sW1[128][65];
  __shared__ float sW2[16][129];
  __shared__ float sb1[128], sb2[16];
  __shared__ float sc[2][64];
  __shared__ float srh[2][128];
  const int t = threadIdx.x;
  for (int i = t; i < 128 * 64; i += 256) sW1[i >> 6][i & 63] = Wr1[i];
  for (int i = t; i < 16 * 128; i += 256) sW2[i >> 7][i & 127] = Wr2[i];
  if (t < 128) sb1[t] = br1[t];
  else if (t < 144) sb2[t - 128] = br2[t - 128];
  const int rowBase = blockIdx.x * 16;
  for (int r0 = 0; r0 < 16; r0 += 2) {
    __syncthreads();
    if (t < 128) sc[t >> 6][t & 63] = cond[(size_t)(rowBase + r0 + (t >> 6)) * 64 + (t & 63)];
    __syncthreads();
    {
      const int half = t >> 7, j = t & 127;
      float a = sb1[j];
      #pragma unroll 16
      for (int c = 0; c < 64; ++c) a = fmaf(sc[half][c], sW1[j][c], a);
      srh[half][j] = fmaxf(a, 0.f);
    }
    __syncthreads();
    if (t < 32) {
      const int half = t >> 4, e = t & 15;
      float a = sb2[e];
      #pragma unroll 16
      for (int k = 0; k < 128; ++k) a = fmaf(srh[half][k], sW2[e][k], a);
      float mx = a;
      #pragma unroll
      for (int m = 8; m; m >>= 1) mx = fmaxf(mx, __shfl_xor(mx, m, 16));
      float p = __expf(a - mx);
      float s = p;
      #pragma unroll
      for (int m = 8; m; m >>= 1) s += __shfl_xor(s, m, 16);
      route[(size_t)(rowBase + r0 + half) * 16 + e] = p / s;
    }
  }
}

// ---- 256x256 GEMM-BT, 16 waves (4 wr x 4 wc), wave-out 64x64, BK=64, dbuf ----
// (exact R13 structure: best measured 79.7 us/dispatch)
// 4 waves/SIMD in ONE block -> intra-CU TLP. Per K64-tile per wave:
// 16 ds_read_b128 + 16 MFMA(32x32x16), one __syncthreads.
// LDS per buf 64KB: A 256x128B @0, B 256x128B @+32KB; buf stride 64KB.
// Swizzle: 128B rows, 8 slots; store slot=(tid&7)^(row&7); read kterm XOR (l&7)<<4.
// C/D: col=l&31, row=(r&3)+8*(r>>2)+4*(l>>5) [HW-verified m74/m101].
// EPI=1: bf16 relu(acc+b1)*route -> Hp; EPI=2: split-K x2 (chunk0 f32, chunk1 bf16).

#define STAGE_TILE_P(buf_)                                                        \
  do {                                                                            \
    gload_lds16(pB0, lds + (buf_) * 32768 + 16384 + tid * 8);                     \
    gload_lds16(pB1, lds + (buf_) * 32768 + 24576 + tid * 8);                     \
    gload_lds16(pA0, lds + (buf_) * 32768 + tid * 8);                             \
    gload_lds16(pA1, lds + (buf_) * 32768 + 8192 + tid * 8);                      \
    pA0 += 64; pA1 += 64; pB0 += 64; pB1 += 64;                                   \
  } while (0)

#define LDA32(dst_, buf_, ksv_, mt_)                                              \
  dst_ = *reinterpret_cast<const short8*>(                                        \
      ldsC + ((buf_) << 16) + aKs[ksv_] + ((mt_) << 12))

#define LDB32(dst_, buf_, ksv_, nt_)                                              \
  dst_ = *reinterpret_cast<const short8*>(                                        \
      ldsC + ((buf_) << 16) + bKs[ksv_] + ((nt_) << 12))

#define LDAB2(dstA_, dstB_, buf_, ksv_)                                           \
  do {                                                                            \
    LDA32(dstA_[0], buf_, ksv_, 0); LDA32(dstA_[1], buf_, ksv_, 1);               \
    LDB32(dstB_[0], buf_, ksv_, 0); LDB32(dstB_[1], buf_, ksv_, 1);               \
  } while (0)

#define MFMA4(AF_, BF_)                                                           \
  _Pragma("unroll") for (int mt_ = 0; mt_ < 2; ++mt_)                             \
  _Pragma("unroll") for (int nt_ = 0; nt_ < 2; ++nt_)                             \
    acc[mt_][nt_] = __builtin_amdgcn_mfma_f32_32x32x16_bf16(                      \
        AF_[mt_], BF_[nt_], acc[mt_][nt_], 0, 0, 0);

#define TILE_COMPUTE(c_)                                                          \
  do {                                                                            \
    LDAB2(aP_, bP_, (c_), 0);                                                     \
    LDAB2(aN_, bN_, (c_), 1);                                                     \
    MFMA4(aP_, bP_);                                                              \
    LDAB2(aP_, bP_, (c_), 2);                                                     \
    MFMA4(aN_, bN_);                                                              \
    LDAB2(aN_, bN_, (c_), 3);                                                     \
    MFMA4(aP_, bP_);                                                              \
    MFMA4(aN_, bN_);                                                              \
  } while (0)

template <int EPI>
__global__ __launch_bounds__(1024, 4)
void k_gemm16(const bfu* __restrict__ A, int lda,
              const bfu* __restrict__ Bm, int ldb,
              int nkt,                      // K64-tiles (per chunk), even, >= 2
              float* __restrict__ outF, bfu* __restrict__ outB, int ldc,
              const float* __restrict__ route, const float* __restrict__ bias1) {
  __shared__ __align__(16) bfu lds[65536];  // 128 KiB: 2 bufs x (A 32KB | B 32KB)
  const char* ldsC = reinterpret_cast<const char*>(lds);
  const int tid = (int)threadIdx.x;
  const int w = tid >> 6, l = tid & 63;
  const int wr = w >> 2, wc = w & 3;                 // 4 x 4 waves
  const int l31 = l & 31, lhi = l >> 5;
  const unsigned axor = (unsigned)((l & 7) << 4);

  unsigned aKs[4], bKs[4];
  #pragma unroll
  for (int ks = 0; ks < 4; ++ks) {
    const unsigned kterm = ((unsigned)((ks << 5) | (lhi << 4))) ^ axor;
    aKs[ks] = (unsigned)((wr * 64 + l31) * 128) + kterm;
    bKs[ks] = (unsigned)(32768 + (wc * 64 + l31) * 128) + kterm;
  }

  const int bid = (int)blockIdx.x;
  const int xcd = bid & 7;
  int brow, bcol, chunk = 0, kOff = 0;
  if (EPI == 1) {
    const int i = bid >> 3;                       // grid 512: XCD owns 8x8 squares
    brow = (((xcd >> 1) << 3) + (i >> 3)) << 8;
    bcol = (((xcd & 1) << 3) + (i & 7)) << 8;
  } else {
    const int i = bid >> 3;                       // grid 256: 4-row slab per chunk
    chunk = i >> 4;
    const int ii = i & 15;
    brow = ((xcd << 2) + (ii >> 2)) << 8;
    bcol = (ii & 3) << 8;
    kOff = chunk * (nkt << 6);
  }

  // hoisted per-lane staging addresses (tile 0), swizzled source slot
  const int srow = tid >> 3;                                     // 0..127
  const int sswz = ((tid & 7) ^ (srow & 7)) << 3;                // element offset
  const bfu* pA0 = A + (size_t)(brow + srow) * lda + kOff + sswz;
  const bfu* pA1 = pA0 + (size_t)128 * lda;
  const bfu* pB0 = Bm + (size_t)(bcol + srow) * ldb + kOff + sswz;
  const bfu* pB1 = pB0 + (size_t)128 * ldb;

  f32x16 acc[2][2] = {};
  short8 aP_[2], aN_[2], bP_[2], bN_[2];

  STAGE_TILE_P(0);
  __syncthreads();

  for (int it = 0; it < (nkt >> 1); ++it) {
    const int T = it << 1;
    STAGE_TILE_P(1);
    TILE_COMPUTE(0);
    __syncthreads();
    if (T + 2 < nkt) STAGE_TILE_P(0);
    TILE_COMPUTE(1);
    __syncthreads();
  }

  // ---------- coalesced epilogue via padded LDS bounce ----------
  if (EPI == 1 || chunk == 1) {
    // bf16: 2 slices of 128 rows; stride 264 bfu (67.6 KB)
    const int STR = 264;
    #pragma unroll
    for (int s = 0; s < 2; ++s) {
      if ((wr >> 1) == s) {
        #pragma unroll
        for (int mt = 0; mt < 2; ++mt) {
          #pragma unroll
          for (int nt = 0; nt < 2; ++nt) {
            const int col = wc * 64 + nt * 32 + l31;
            float bz = 0.f;
            if (EPI == 1) bz = bias1[bcol + col];
            #pragma unroll
            for (int r = 0; r < 16; ++r) {
              const int rloc = (r & 3) + 8 * (r >> 2) + 4 * lhi;     // 0..31
              const int lrow = (wr & 1) * 64 + mt * 32 + rloc;       // 0..127
              float v = acc[mt][nt][r];
              if (EPI == 1) {
                const int rowg = brow + s * 128 + lrow;
                v = fmaxf(v + bz, 0.f) * route[(size_t)rowg * E_ + (bcol >> 8)];
              }
              lds[lrow * STR + col] = f2b(v);
            }
          }
        }
      }
      __syncthreads();
      #pragma unroll
      for (int i = 0; i < 4; ++i) {
        const int id = i * 1024 + tid;            // 4096 x 16B chunks
        const int row = id >> 5, c16 = id & 31;   // row 0..127
        *reinterpret_cast<short8*>(outB + (size_t)(brow + s * 128 + row) * ldc +
                                   bcol + c16 * 8) =
            *reinterpret_cast<const short8*>(lds + row * STR + c16 * 8);
      }
      __syncthreads();
    }
  } else {
    // f32: 4 slices of 64 rows keyed by wr; stride 260 f32 (66.5 KB)
    const int STRF = 260;
    float* sF = reinterpret_cast<float*>(lds);
    #pragma unroll
    for (int s = 0; s < 4; ++s) {
      if (wr == s) {
        #pragma unroll
        for (int mt = 0; mt < 2; ++mt) {
          #pragma unroll
          for (int nt = 0; nt < 2; ++nt) {
            const int col = wc * 64 + nt * 32 + l31;
            #pragma unroll
            for (int r = 0; r < 16; ++r) {
              const int rloc = (r & 3) + 8 * (r >> 2) + 4 * lhi;     // 0..31
              sF[(mt * 32 + rloc) * STRF + col] = acc[mt][nt][r];
            }
          }
        }
      }
      __syncthreads();
      #pragma unroll
      for (int i = 0; i < 4; ++i) {
        const int id = i * 1024 + tid;            // 4096 x 16B chunks
        const int row = id >> 6, c4 = id & 63;    // row 0..63
        *reinterpret_cast<float4*>(outF + (size_t)(brow + s * 64 + row) * ldc +
                                   bcol + c4 * 4) =
            *reinterpret_cast<const float4*>(sF + row * STRF + c4 * 4);
      }
      __syncthreads();
    }
  }
}

// ---------------- reduce: out += P1 + route @ b2 ----------------
__global__ __launch_bounds__(256)
void k_reduce(float* __restrict__ out, const bfu* __restrict__ P1,
              const float* __restrict__ route, const float* __restrict__ b2) {
  __shared__ float sb2[E_ * D_];   // 64 KiB
  for (int i = threadIdx.x; i < E_ * D_; i += 256) sb2[i] = b2[i];
  __syncthreads();
  const int total = (B_ * D_) / 4;
  for (int idx = blockIdx.x * 256 + threadIdx.x; idx < total; idx += gridDim.x * 256) {
    const int b = idx >> 8;
    const int d4 = (idx & 255) * 4;
    float4 o = reinterpret_cast<float4*>(out)[idx];
    ushort4 p = reinterpret_cast<const ushort4*>(P1)[idx];
    o.x += b2f(p.x); o.y += b2f(p.y); o.z += b2f(p.z); o.w += b2f(p.w);
    const float* rr = route + (size_t)b * E_;
    #pragma unroll
    for (int e = 0; e < E_; ++e) {
      const float r = rr[e];
      const float* bb = sb2 + e * D_ + d4;
      o.x = fmaf(r, bb[0], o.x);
      o.y = fmaf(r, bb[1], o.y);
      o.z = fmaf(r, bb[2], o.z);
      o.w = fmaf(r, bb[3], o.w);
    }
    reinterpret_cast<float4*>(out)[idx] = o;
  }
}

// ---------------- launch ----------------
extern "C" void kernel_launch(void* const* d_in, const int* in_sizes, int n_in,
                              void* d_out, int out_size, void* d_ws, size_t ws_size,
                              hipStream_t stream) {
  const float* x    = (const float*)d_in[0];
  const float* cond = (const float*)d_in[1];
  const float* W1   = (const float*)d_in[2];
  const float* b1   = (const float*)d_in[3];
  const float* W2   = (const float*)d_in[4];
  const float* b2   = (const float*)d_in[5];
  const float* Wr1  = (const float*)d_in[6];
  const float* br1  = (const float*)d_in[7];
  const float* Wr2  = (const float*)d_in[8];
  const float* br2  = (const float*)d_in[9];
  float* out = (float*)d_out;

  // ws layout (96.5 MB):
  // [Hp 64MB][W2t 8MB][route 0.5MB][W1b 8MB][xb 16MB (= P1 after GEMM1)]
  char* p = (char*)d_ws;
  bfu*   Hp    = (bfu*)p;                 p += (size_t)B_ * EH_ * 2;
  bfu*   W2t   = (bfu*)p;                 p += (size_t)D_ * EH_ * 2;
  float* route = (float*)p;               p += (size_t)B_ * E_ * 4;
  bfu*   W1b   = (bfu*)p;                 p += (size_t)EH_ * D_ * 2;
  bfu*   xb    = (bfu*)p;                 /* B_*D_*2 = 16MB */
  bfu*   P1b   = xb;                      // alias: xb dead after GEMM1

  k_prep<<<2048, 256, 0, stream>>>(x, xb, W1, W1b, W2, W2t);
  k_router<<<B_ / 16, 256, 0, stream>>>(cond, Wr1, br1, Wr2, br2, route);

  // GEMM1: Hp[8192,4096] = relu(xb @ W1b^T + b1) * route   (512 blocks)
  k_gemm16<1><<<dim3((B_ / 256) * (EH_ / 256)), 1024, 0, stream>>>(
      xb, D_, W1b, D_, D_ / 64, nullptr, Hp, EH_, route, b1);

  // GEMM2: out/P1 = Hp @ W2t^T, split-K x2  (256 blocks)
  k_gemm16<2><<<dim3((B_ / 256) * (D_ / 256) * 2), 1024, 0, stream>>>(
      Hp, EH_, W2t, EH_, (EH_ / 64) / 2, out, P1b, D_, nullptr, nullptr);

  // out += P1 + route @ b2
  k_reduce<<<1024, 256, 0, stream>>>(out, P1b, route, b2);
}